// Round 9
// baseline (433.351 us; speedup 1.0000x reference)
//
#include <hip/hip_runtime.h>
#include <hip/hip_fp16.h>

typedef _Float16 f16;
typedef __attribute__((ext_vector_type(8))) _Float16 f16x8;
typedef __attribute__((ext_vector_type(4))) _Float16 f16x4;
typedef __attribute__((ext_vector_type(2))) __fp16 fp16x2;
typedef __attribute__((ext_vector_type(4))) float f32x4;

// ---------------------------------------------------------------------------
// Pre-pass A (fallback only): h (fp32) -> f16.
// ---------------------------------------------------------------------------
__global__ void cvt_h_f16(const float* __restrict__ h, f16* __restrict__ hf, int n4) {
    int stride = gridDim.x * blockDim.x;
    for (int i = blockIdx.x * blockDim.x + threadIdx.x; i < n4; i += stride) {
        float4 v = reinterpret_cast<const float4*>(h)[i];
        f16x4 o = { (f16)v.x, (f16)v.y, (f16)v.z, (f16)v.w };
        reinterpret_cast<f16x4*>(hf)[i] = o;
    }
}

// ---------------------------------------------------------------------------
// Pre-pass B: per-node layer-1 halves (proven round-8).
//   u[n] = W1[:, :128] @ h[n] + b1 ;  v[n] = W1[:,128:] @ h[n]
// ---------------------------------------------------------------------------
__global__ __launch_bounds__(256, 2)
void build_uv(const float* __restrict__ h, const float* __restrict__ W1,
              const float* __restrict__ b1,
              f16* __restrict__ U, f16* __restrict__ V, int nNodes)
{
    __shared__ f16 hS[64 * 128];
    __shared__ f16 xS[64 * 128];

    const int tid = threadIdx.x;
    const int w = tid >> 6, l = tid & 63, g = l >> 4, c = l & 15;

    f16x8 waf[4][2], wbf[4][2];
    f32x4 b1v[2];
    #pragma unroll
    for (int nt = 0; nt < 2; ++nt) {
        const int n = w * 32 + nt * 16 + c;
        #pragma unroll
        for (int ks = 0; ks < 4; ++ks) {
            const float4* pa = reinterpret_cast<const float4*>(W1 + n * 256 + ks * 32 + g * 8);
            const float4* pb = reinterpret_cast<const float4*>(W1 + n * 256 + 128 + ks * 32 + g * 8);
            float4 a0 = pa[0], a1 = pa[1], b0 = pb[0], b1_ = pb[1];
            f16x8 va = { (f16)a0.x,(f16)a0.y,(f16)a0.z,(f16)a0.w,
                         (f16)a1.x,(f16)a1.y,(f16)a1.z,(f16)a1.w };
            f16x8 vb = { (f16)b0.x,(f16)b0.y,(f16)b0.z,(f16)b0.w,
                         (f16)b1_.x,(f16)b1_.y,(f16)b1_.z,(f16)b1_.w };
            waf[ks][nt] = va;
            wbf[ks][nt] = vb;
        }
        b1v[nt] = *reinterpret_cast<const f32x4*>(b1 + w * 32 + nt * 16 + g * 4);
    }

    const int node0 = blockIdx.x * 64;
    {
        const int m = tid >> 2, q4 = tid & 3;
        const int node = node0 + m;
        if (node < nNodes) {
            const float4* src = reinterpret_cast<const float4*>(h + (size_t)node * 128) + q4 * 8;
            #pragma unroll
            for (int j = 0; j < 4; ++j) {
                float4 a = src[2 * j], b = src[2 * j + 1];
                f16x8 v = { (f16)a.x,(f16)a.y,(f16)a.z,(f16)a.w,
                            (f16)b.x,(f16)b.y,(f16)b.z,(f16)b.w };
                const int chs = (q4 * 4 + j) ^ (m & 7);
                *reinterpret_cast<f16x8*>(&hS[m * 128 + chs * 8]) = v;
            }
        } else {
            #pragma unroll
            for (int j = 0; j < 4; ++j) {
                const int chs = (q4 * 4 + j) ^ (m & 7);
                *reinterpret_cast<f16x8*>(&hS[m * 128 + chs * 8]) = (f16x8)(f16)0;
            }
        }
    }
    __syncthreads();

    f32x4 acc[4][2];
    // U
    #pragma unroll
    for (int et = 0; et < 4; ++et) { acc[et][0] = (f32x4){0,0,0,0}; acc[et][1] = (f32x4){0,0,0,0}; }
    #pragma unroll
    for (int ks = 0; ks < 4; ++ks) {
        #pragma unroll
        for (int et = 0; et < 4; ++et) {
            const int row = et * 16 + c;
            const int chs = (ks * 4 + g) ^ (row & 7);
            f16x8 hb = *reinterpret_cast<const f16x8*>(&hS[row * 128 + chs * 8]);
            acc[et][0] = __builtin_amdgcn_mfma_f32_16x16x32_f16(waf[ks][0], hb, acc[et][0], 0, 0, 0);
            acc[et][1] = __builtin_amdgcn_mfma_f32_16x16x32_f16(waf[ks][1], hb, acc[et][1], 0, 0, 0);
        }
    }
    #pragma unroll
    for (int et = 0; et < 4; ++et) {
        #pragma unroll
        for (int nt = 0; nt < 2; ++nt) {
            f32x4 v = acc[et][nt] + b1v[nt];
            f16x4 p = { (f16)v[0], (f16)v[1], (f16)v[2], (f16)v[3] };
            const int row = et * 16 + c;
            const int n0 = w * 32 + nt * 16 + g * 4;
            const int chs = (n0 >> 3) ^ (row & 7);
            *reinterpret_cast<f16x4*>(&xS[row * 128 + chs * 8 + (n0 & 7)]) = p;
        }
    }
    __syncthreads();
    {
        const int m = tid >> 2, q4 = tid & 3;
        const int node = node0 + m;
        if (node < nNodes) {
            #pragma unroll
            for (int j = 0; j < 4; ++j) {
                const int lc = q4 * 4 + j;
                const int chs = lc ^ (m & 7);
                uint4 val = *reinterpret_cast<const uint4*>(&xS[m * 128 + chs * 8]);
                reinterpret_cast<uint4*>(U + (size_t)node * 128)[lc] = val;
            }
        }
    }
    __syncthreads();

    // V
    #pragma unroll
    for (int et = 0; et < 4; ++et) { acc[et][0] = (f32x4){0,0,0,0}; acc[et][1] = (f32x4){0,0,0,0}; }
    #pragma unroll
    for (int ks = 0; ks < 4; ++ks) {
        #pragma unroll
        for (int et = 0; et < 4; ++et) {
            const int row = et * 16 + c;
            const int chs = (ks * 4 + g) ^ (row & 7);
            f16x8 hb = *reinterpret_cast<const f16x8*>(&hS[row * 128 + chs * 8]);
            acc[et][0] = __builtin_amdgcn_mfma_f32_16x16x32_f16(wbf[ks][0], hb, acc[et][0], 0, 0, 0);
            acc[et][1] = __builtin_amdgcn_mfma_f32_16x16x32_f16(wbf[ks][1], hb, acc[et][1], 0, 0, 0);
        }
    }
    #pragma unroll
    for (int et = 0; et < 4; ++et) {
        #pragma unroll
        for (int nt = 0; nt < 2; ++nt) {
            f32x4 v = acc[et][nt];
            f16x4 p = { (f16)v[0], (f16)v[1], (f16)v[2], (f16)v[3] };
            const int row = et * 16 + c;
            const int n0 = w * 32 + nt * 16 + g * 4;
            const int chs = (n0 >> 3) ^ (row & 7);
            *reinterpret_cast<f16x4*>(&xS[row * 128 + chs * 8 + (n0 & 7)]) = p;
        }
    }
    __syncthreads();
    {
        const int m = tid >> 2, q4 = tid & 3;
        const int node = node0 + m;
        if (node < nNodes) {
            #pragma unroll
            for (int j = 0; j < 4; ++j) {
                const int lc = q4 * 4 + j;
                const int chs = lc ^ (m & 7);
                uint4 val = *reinterpret_cast<const uint4*>(&xS[m * 128 + chs * 8]);
                reinterpret_cast<uint4*>(V + (size_t)node * 128)[lc] = val;
            }
        }
    }
}

// ---------------------------------------------------------------------------
// Edge kernel v2: ZERO-LDS gather — u/v fragments loaded straight into MFMA
// B-operand registers. Lane (g,c), fragment ks of edge row e: 16B at
// byte offset ks*64 + g*16 (uint4 index ks*4+g). x1 = relu(u+v) in packed
// f16 regs. Per-wave n2-slice [32w,32w+32); cross-wave sum via 2 KB parity
// sbuf, ONE barrier per tile. No LDS tiles -> no bank conflicts, no staging
// VALU; occupancy 4 blocks/CU x 4 waves (VGPR-capped via launch_bounds).
// ---------------------------------------------------------------------------
__global__ __launch_bounds__(256, 4)
void mlp_edges_uv2(const f16* __restrict__ U, const f16* __restrict__ V,
                   const int* __restrict__ srcI, const int* __restrict__ dstI,
                   const float* __restrict__ W2, const float* __restrict__ b2,
                   const float* __restrict__ W3, const float* __restrict__ b3,
                   float* __restrict__ out, int E, int ntiles)
{
    __shared__ float sbuf[2][4][64];   // 2 KB, parity double-buffered

    const int tid = threadIdx.x;
    const int w = tid >> 6, l = tid & 63, g = l >> 4, c = l & 15;
    const int grid = gridDim.x;

    // ---- W2 fragments + layer-3 constants ----
    f16x8 w2f[4][2];
    f32x4 b2v[2], w3v[2];
    #pragma unroll
    for (int nt = 0; nt < 2; ++nt) {
        const int n = w * 32 + nt * 16 + c;
        #pragma unroll
        for (int ks = 0; ks < 4; ++ks) {
            const float4* p = reinterpret_cast<const float4*>(W2 + n * 128 + ks * 32 + g * 8);
            float4 a = p[0], b = p[1];
            f16x8 v = { (f16)a.x,(f16)a.y,(f16)a.z,(f16)a.w,
                        (f16)b.x,(f16)b.y,(f16)b.z,(f16)b.w };
            w2f[ks][nt] = v;
        }
        const int base = w * 32 + nt * 16 + g * 4;
        b2v[nt] = *reinterpret_cast<const f32x4*>(b2 + base);
        w3v[nt] = *reinterpret_cast<const f32x4*>(W3 + base);
    }
    const float b3s = b3[0];

    int par = 0;
    for (int t = blockIdx.x; t < ntiles; t += grid, par ^= 1) {
        const int e0 = t * 64;

        f32x4 acc[4][2];
        #pragma unroll
        for (int et = 0; et < 4; ++et) { acc[et][0] = (f32x4){0,0,0,0}; acc[et][1] = (f32x4){0,0,0,0}; }

        #pragma unroll
        for (int et = 0; et < 4; ++et) {
            const int e = e0 + et * 16 + c;
            const bool eok = (e < E);
            const int si = eok ? srcI[e] : 0;
            const int di = eok ? dstI[e] : 0;
            const uint4* up = reinterpret_cast<const uint4*>(U + (size_t)si * 128);
            const uint4* vp = reinterpret_cast<const uint4*>(V + (size_t)di * 128);
            uint4 uf[4], vf[4];
            #pragma unroll
            for (int ks = 0; ks < 4; ++ks) {
                uf[ks] = up[ks * 4 + g];
                vf[ks] = vp[ks * 4 + g];
            }
            #pragma unroll
            for (int ks = 0; ks < 4; ++ks) {
                f16x8 xf = *reinterpret_cast<f16x8*>(&uf[ks]) + *reinterpret_cast<f16x8*>(&vf[ks]);
                #pragma unroll
                for (int j = 0; j < 8; ++j) xf[j] = xf[j] > (f16)0 ? xf[j] : (f16)0;
                acc[et][0] = __builtin_amdgcn_mfma_f32_16x16x32_f16(w2f[ks][0], xf, acc[et][0], 0, 0, 0);
                acc[et][1] = __builtin_amdgcn_mfma_f32_16x16x32_f16(w2f[ks][1], xf, acc[et][1], 0, 0, 0);
            }
        }

        // ---- layer 3 (fp32) + in-wave reduce ----
        #pragma unroll
        for (int et = 0; et < 4; ++et) {
            f32x4 sv = {0.f,0.f,0.f,0.f};
            #pragma unroll
            for (int nt = 0; nt < 2; ++nt) {
                f32x4 v = acc[et][nt] + b2v[nt];
                #pragma unroll
                for (int r = 0; r < 4; ++r) {
                    float x = v[r] > 0.f ? v[r] : 0.f;
                    sv[r] += x * w3v[nt][r];
                }
            }
            float part = sv[0] + sv[1] + sv[2] + sv[3];
            part += __shfl_xor(part, 16, 64);
            part += __shfl_xor(part, 32, 64);
            if (g == 0) sbuf[par][w][et * 16 + c] = part;
        }
        __syncthreads();   // sbuf[par] ready (next tile writes par^1 -> safe)

        if (tid < 64) {
            const int e = e0 + tid;
            if (e < E)
                out[e] = sbuf[par][0][tid] + sbuf[par][1][tid]
                       + sbuf[par][2][tid] + sbuf[par][3][tid] + b3s;
        }
    }
}

// ---------------------------------------------------------------------------
// Fallback (ws too small for U+V): round-7 proven kernel.
// ---------------------------------------------------------------------------
template<int USEF16>
__global__ __launch_bounds__(256, 3)
void mlp_edges(const float* __restrict__ h32, const f16* __restrict__ hf,
               const int* __restrict__ srcI, const int* __restrict__ dstI,
               const float* __restrict__ W1, const float* __restrict__ b1,
               const float* __restrict__ W2, const float* __restrict__ b2,
               const float* __restrict__ W3, const float* __restrict__ b3,
               float* __restrict__ out, int E, int ntiles)
{
    __shared__ f16 heS[64 * 256];
    __shared__ f16 x1S[64 * 128];
    __shared__ float sbuf[4][64];

    const int tid = threadIdx.x;
    const int w = tid >> 6, l = tid & 63, g = l >> 4, c = l & 15;
    const int grid = gridDim.x;

    f16x8 w1f[8][2], w2f[4][2];
    f32x4 b1v[2], b2v[2], w3v[2];
    #pragma unroll
    for (int nt = 0; nt < 2; ++nt) {
        const int n = w * 32 + nt * 16 + c;
        #pragma unroll
        for (int ks = 0; ks < 8; ++ks) {
            const float4* p = reinterpret_cast<const float4*>(W1 + n * 256 + ks * 32 + g * 8);
            float4 a = p[0], b = p[1];
            f16x8 v = { (f16)a.x,(f16)a.y,(f16)a.z,(f16)a.w,
                        (f16)b.x,(f16)b.y,(f16)b.z,(f16)b.w };
            w1f[ks][nt] = v;
        }
        #pragma unroll
        for (int ks = 0; ks < 4; ++ks) {
            const float4* p = reinterpret_cast<const float4*>(W2 + n * 128 + ks * 32 + g * 8);
            float4 a = p[0], b = p[1];
            f16x8 v = { (f16)a.x,(f16)a.y,(f16)a.z,(f16)a.w,
                        (f16)b.x,(f16)b.y,(f16)b.z,(f16)b.w };
            w2f[ks][nt] = v;
        }
        const int base = w * 32 + nt * 16 + g * 4;
        b1v[nt] = *reinterpret_cast<const f32x4*>(b1 + base);
        b2v[nt] = *reinterpret_cast<const f32x4*>(b2 + base);
        w3v[nt] = *reinterpret_cast<const f32x4*>(W3 + base);
    }
    const float b3s = b3[0];

    const int p_ = tid >> 1, q_ = tid & 1;
    const int m_ = p_ & 63;
    const int hh = p_ >> 6;
    const int* __restrict__ idxArr = hh ? dstI : srcI;

    auto loadIdx = [&](int t) -> int {
        int e = t * 64 + m_;
        return (e < E) ? idxArr[e] : 0;
    };
    auto stage = [&](int node) {
        if (USEF16) {
            const uint4* src = reinterpret_cast<const uint4*>(hf + (size_t)node * 128) + q_ * 8;
            #pragma unroll
            for (int j = 0; j < 8; ++j) {
                uint4 v = src[j];
                const int chs = (hh * 16 + q_ * 8 + j) ^ (m_ & 7);
                *reinterpret_cast<uint4*>(&heS[m_ * 256 + chs * 8]) = v;
            }
        } else {
            const float4* src = reinterpret_cast<const float4*>(h32 + (size_t)node * 128) + q_ * 16;
            #pragma unroll
            for (int j = 0; j < 8; ++j) {
                float4 a = src[2 * j], b = src[2 * j + 1];
                f16x8 v = { (f16)a.x,(f16)a.y,(f16)a.z,(f16)a.w,
                            (f16)b.x,(f16)b.y,(f16)b.z,(f16)b.w };
                const int chs = (hh * 16 + q_ * 8 + j) ^ (m_ & 7);
                *reinterpret_cast<f16x8*>(&heS[m_ * 256 + chs * 8]) = v;
            }
        }
    };

    const int t0 = blockIdx.x;
    int nIdx = (t0 < ntiles) ? loadIdx(t0) : 0;

    for (int t = t0; t < ntiles; t += grid) {
        stage(nIdx);
        __syncthreads();
        nIdx = (t + grid < ntiles) ? loadIdx(t + grid) : 0;

        f32x4 acc[4][2];
        #pragma unroll
        for (int et = 0; et < 4; ++et) { acc[et][0] = (f32x4){0,0,0,0}; acc[et][1] = (f32x4){0,0,0,0}; }
        #pragma unroll
        for (int ks = 0; ks < 8; ++ks) {
            #pragma unroll
            for (int et = 0; et < 4; ++et) {
                const int edge = et * 16 + c;
                const int chs = (ks * 4 + g) ^ (edge & 7);
                f16x8 hb = *reinterpret_cast<const f16x8*>(&heS[edge * 256 + chs * 8]);
                acc[et][0] = __builtin_amdgcn_mfma_f32_16x16x32_f16(w1f[ks][0], hb, acc[et][0], 0, 0, 0);
                acc[et][1] = __builtin_amdgcn_mfma_f32_16x16x32_f16(w1f[ks][1], hb, acc[et][1], 0, 0, 0);
            }
        }
        #pragma unroll
        for (int et = 0; et < 4; ++et) {
            #pragma unroll
            for (int nt = 0; nt < 2; ++nt) {
                f32x4 v = acc[et][nt] + b1v[nt];
                #pragma unroll
                for (int r = 0; r < 4; ++r) v[r] = v[r] > 0.f ? v[r] : 0.f;
                union { fp16x2 h2[2]; uint2 u; } uu;
                uu.h2[0] = __builtin_amdgcn_cvt_pkrtz(v[0], v[1]);
                uu.h2[1] = __builtin_amdgcn_cvt_pkrtz(v[2], v[3]);
                const int edge = et * 16 + c;
                const int n0 = w * 32 + nt * 16 + g * 4;
                const int chs = (n0 >> 3) ^ (edge & 7);
                *reinterpret_cast<uint2*>(&x1S[edge * 128 + chs * 8 + (n0 & 7)]) = uu.u;
            }
        }
        __syncthreads();

        #pragma unroll
        for (int et = 0; et < 4; ++et) { acc[et][0] = (f32x4){0,0,0,0}; acc[et][1] = (f32x4){0,0,0,0}; }
        #pragma unroll
        for (int ks = 0; ks < 4; ++ks) {
            #pragma unroll
            for (int et = 0; et < 4; ++et) {
                const int edge = et * 16 + c;
                const int chs = (ks * 4 + g) ^ (edge & 7);
                f16x8 xb = *reinterpret_cast<const f16x8*>(&x1S[edge * 128 + chs * 8]);
                acc[et][0] = __builtin_amdgcn_mfma_f32_16x16x32_f16(w2f[ks][0], xb, acc[et][0], 0, 0, 0);
                acc[et][1] = __builtin_amdgcn_mfma_f32_16x16x32_f16(w2f[ks][1], xb, acc[et][1], 0, 0, 0);
            }
        }
        #pragma unroll
        for (int et = 0; et < 4; ++et) {
            f32x4 sv = {0.f,0.f,0.f,0.f};
            #pragma unroll
            for (int nt = 0; nt < 2; ++nt) {
                f32x4 v = acc[et][nt] + b2v[nt];
                #pragma unroll
                for (int r = 0; r < 4; ++r) {
                    float x = v[r] > 0.f ? v[r] : 0.f;
                    sv[r] += x * w3v[nt][r];
                }
            }
            float part = sv[0] + sv[1] + sv[2] + sv[3];
            part += __shfl_xor(part, 16, 64);
            part += __shfl_xor(part, 32, 64);
            if (g == 0) sbuf[w][et * 16 + c] = part;
        }
        __syncthreads();

        if (tid < 64) {
            const int e = t * 64 + tid;
            if (e < E)
                out[e] = sbuf[0][tid] + sbuf[1][tid] + sbuf[2][tid] + sbuf[3][tid] + b3s;
        }
    }
}

// ---------------------------------------------------------------------------
extern "C" void kernel_launch(void* const* d_in, const int* in_sizes, int n_in,
                              void* d_out, int out_size, void* d_ws, size_t ws_size,
                              hipStream_t stream) {
    const float* h  = (const float*)d_in[0];
    const int* srcI = (const int*)d_in[1];
    const int* dstI = (const int*)d_in[2];
    const float* W1 = (const float*)d_in[3];
    const float* b1 = (const float*)d_in[4];
    const float* W2 = (const float*)d_in[5];
    const float* b2 = (const float*)d_in[6];
    const float* W3 = (const float*)d_in[7];
    const float* b3 = (const float*)d_in[8];
    float* out = (float*)d_out;

    const int E = in_sizes[1];
    const int hElems = in_sizes[0];        // nNodes * 128
    const int nNodes = hElems / 128;
    const int ntiles = (E + 63) / 64;

    const size_t uvBytes = 2 * (size_t)nNodes * 128 * sizeof(f16);   // U + V
    if (ws_size >= uvBytes) {
        f16* U = (f16*)d_ws;
        f16* V = U + (size_t)nNodes * 128;
        build_uv<<<(nNodes + 63) / 64, 256, 0, stream>>>(h, W1, b1, U, V, nNodes);
        const int grid = ntiles < 1024 ? ntiles : 1024;   // 4 blocks/CU
        mlp_edges_uv2<<<grid, 256, 0, stream>>>(U, V, srcI, dstI, W2, b2, W3, b3, out, E, ntiles);
    } else {
        f16* hf = (f16*)d_ws;
        const bool useF16 = (ws_size >= (size_t)hElems * sizeof(f16));
        if (useF16) cvt_h_f16<<<2048, 256, 0, stream>>>(h, hf, hElems / 4);
        const int grid = ntiles < 768 ? ntiles : 768;
        if (useF16)
            mlp_edges<1><<<grid, 256, 0, stream>>>(h, hf, srcI, dstI, W1, b1, W2, b2, W3, b3, out, E, ntiles);
        else
            mlp_edges<0><<<grid, 256, 0, stream>>>(h, hf, srcI, dstI, W1, b1, W2, b2, W3, b3, out, E, ntiles);
    }
}

// Round 12
// 184.191 us; speedup vs baseline: 2.3527x; 2.3527x over previous
//
#include <hip/hip_runtime.h>
#include <hip/hip_fp16.h>

typedef _Float16 f16;
typedef __attribute__((ext_vector_type(8))) _Float16 f16x8;
typedef __attribute__((ext_vector_type(4))) _Float16 f16x4;
typedef __attribute__((ext_vector_type(2))) __fp16 fp16x2;
typedef __attribute__((ext_vector_type(4))) float f32x4;

#define GAS __attribute__((address_space(1)))
#define LAS __attribute__((address_space(3)))

// global_load_lds, 16B per lane. LDS dest = wave-uniform base + lane*16
// (m104/m108); global source is per-lane (m173).
__device__ __forceinline__ void gll16(const f16* g, f16* l) {
    __builtin_amdgcn_global_load_lds(
        (const GAS void*)(uintptr_t)(const void*)g,
        (LAS void*)(uintptr_t)(void*)l, 16, 0, 0);
}

// Explicit DMA drain: do NOT rely on the compiler emitting vmcnt(0) before
// s_barrier for cross-iteration in-flight global_load_lds (round-11 race).
__device__ __forceinline__ void drain_dma_and_barrier() {
    asm volatile("s_waitcnt vmcnt(0)" ::: "memory");
    __syncthreads();
}

// ---------------------------------------------------------------------------
// Pre-pass A (fallback only): h (fp32) -> f16.
// ---------------------------------------------------------------------------
__global__ void cvt_h_f16(const float* __restrict__ h, f16* __restrict__ hf, int n4) {
    int stride = gridDim.x * blockDim.x;
    for (int i = blockIdx.x * blockDim.x + threadIdx.x; i < n4; i += stride) {
        float4 v = reinterpret_cast<const float4*>(h)[i];
        f16x4 o = { (f16)v.x, (f16)v.y, (f16)v.z, (f16)v.w };
        reinterpret_cast<f16x4*>(hf)[i] = o;
    }
}

// ---------------------------------------------------------------------------
// Pre-pass B: per-node layer-1 halves (proven round-8).
//   u[n] = W1[:, :128] @ h[n] + b1 ;  v[n] = W1[:,128:] @ h[n]
// ---------------------------------------------------------------------------
__global__ __launch_bounds__(256, 2)
void build_uv(const float* __restrict__ h, const float* __restrict__ W1,
              const float* __restrict__ b1,
              f16* __restrict__ U, f16* __restrict__ V, int nNodes)
{
    __shared__ f16 hS[64 * 128];
    __shared__ f16 xS[64 * 128];

    const int tid = threadIdx.x;
    const int w = tid >> 6, l = tid & 63, g = l >> 4, c = l & 15;

    f16x8 waf[4][2], wbf[4][2];
    f32x4 b1v[2];
    #pragma unroll
    for (int nt = 0; nt < 2; ++nt) {
        const int n = w * 32 + nt * 16 + c;
        #pragma unroll
        for (int ks = 0; ks < 4; ++ks) {
            const float4* pa = reinterpret_cast<const float4*>(W1 + n * 256 + ks * 32 + g * 8);
            const float4* pb = reinterpret_cast<const float4*>(W1 + n * 256 + 128 + ks * 32 + g * 8);
            float4 a0 = pa[0], a1 = pa[1], b0 = pb[0], b1_ = pb[1];
            f16x8 va = { (f16)a0.x,(f16)a0.y,(f16)a0.z,(f16)a0.w,
                         (f16)a1.x,(f16)a1.y,(f16)a1.z,(f16)a1.w };
            f16x8 vb = { (f16)b0.x,(f16)b0.y,(f16)b0.z,(f16)b0.w,
                         (f16)b1_.x,(f16)b1_.y,(f16)b1_.z,(f16)b1_.w };
            waf[ks][nt] = va;
            wbf[ks][nt] = vb;
        }
        b1v[nt] = *reinterpret_cast<const f32x4*>(b1 + w * 32 + nt * 16 + g * 4);
    }

    const int node0 = blockIdx.x * 64;
    {
        const int m = tid >> 2, q4 = tid & 3;
        const int node = node0 + m;
        if (node < nNodes) {
            const float4* src = reinterpret_cast<const float4*>(h + (size_t)node * 128) + q4 * 8;
            #pragma unroll
            for (int j = 0; j < 4; ++j) {
                float4 a = src[2 * j], b = src[2 * j + 1];
                f16x8 v = { (f16)a.x,(f16)a.y,(f16)a.z,(f16)a.w,
                            (f16)b.x,(f16)b.y,(f16)b.z,(f16)b.w };
                const int chs = (q4 * 4 + j) ^ (m & 7);
                *reinterpret_cast<f16x8*>(&hS[m * 128 + chs * 8]) = v;
            }
        } else {
            #pragma unroll
            for (int j = 0; j < 4; ++j) {
                const int chs = (q4 * 4 + j) ^ (m & 7);
                *reinterpret_cast<f16x8*>(&hS[m * 128 + chs * 8]) = (f16x8)(f16)0;
            }
        }
    }
    __syncthreads();

    f32x4 acc[4][2];
    // U
    #pragma unroll
    for (int et = 0; et < 4; ++et) { acc[et][0] = (f32x4){0,0,0,0}; acc[et][1] = (f32x4){0,0,0,0}; }
    #pragma unroll
    for (int ks = 0; ks < 4; ++ks) {
        #pragma unroll
        for (int et = 0; et < 4; ++et) {
            const int row = et * 16 + c;
            const int chs = (ks * 4 + g) ^ (row & 7);
            f16x8 hb = *reinterpret_cast<const f16x8*>(&hS[row * 128 + chs * 8]);
            acc[et][0] = __builtin_amdgcn_mfma_f32_16x16x32_f16(waf[ks][0], hb, acc[et][0], 0, 0, 0);
            acc[et][1] = __builtin_amdgcn_mfma_f32_16x16x32_f16(waf[ks][1], hb, acc[et][1], 0, 0, 0);
        }
    }
    #pragma unroll
    for (int et = 0; et < 4; ++et) {
        #pragma unroll
        for (int nt = 0; nt < 2; ++nt) {
            f32x4 v = acc[et][nt] + b1v[nt];
            f16x4 p = { (f16)v[0], (f16)v[1], (f16)v[2], (f16)v[3] };
            const int row = et * 16 + c;
            const int n0 = w * 32 + nt * 16 + g * 4;
            const int chs = (n0 >> 3) ^ (row & 7);
            *reinterpret_cast<f16x4*>(&xS[row * 128 + chs * 8 + (n0 & 7)]) = p;
        }
    }
    __syncthreads();
    {
        const int m = tid >> 2, q4 = tid & 3;
        const int node = node0 + m;
        if (node < nNodes) {
            #pragma unroll
            for (int j = 0; j < 4; ++j) {
                const int lc = q4 * 4 + j;
                const int chs = lc ^ (m & 7);
                uint4 val = *reinterpret_cast<const uint4*>(&xS[m * 128 + chs * 8]);
                reinterpret_cast<uint4*>(U + (size_t)node * 128)[lc] = val;
            }
        }
    }
    __syncthreads();

    // V
    #pragma unroll
    for (int et = 0; et < 4; ++et) { acc[et][0] = (f32x4){0,0,0,0}; acc[et][1] = (f32x4){0,0,0,0}; }
    #pragma unroll
    for (int ks = 0; ks < 4; ++ks) {
        #pragma unroll
        for (int et = 0; et < 4; ++et) {
            const int row = et * 16 + c;
            const int chs = (ks * 4 + g) ^ (row & 7);
            f16x8 hb = *reinterpret_cast<const f16x8*>(&hS[row * 128 + chs * 8]);
            acc[et][0] = __builtin_amdgcn_mfma_f32_16x16x32_f16(wbf[ks][0], hb, acc[et][0], 0, 0, 0);
            acc[et][1] = __builtin_amdgcn_mfma_f32_16x16x32_f16(wbf[ks][1], hb, acc[et][1], 0, 0, 0);
        }
    }
    #pragma unroll
    for (int et = 0; et < 4; ++et) {
        #pragma unroll
        for (int nt = 0; nt < 2; ++nt) {
            f32x4 v = acc[et][nt];
            f16x4 p = { (f16)v[0], (f16)v[1], (f16)v[2], (f16)v[3] };
            const int row = et * 16 + c;
            const int n0 = w * 32 + nt * 16 + g * 4;
            const int chs = (n0 >> 3) ^ (row & 7);
            *reinterpret_cast<f16x4*>(&xS[row * 128 + chs * 8 + (n0 & 7)]) = p;
        }
    }
    __syncthreads();
    {
        const int m = tid >> 2, q4 = tid & 3;
        const int node = node0 + m;
        if (node < nNodes) {
            #pragma unroll
            for (int j = 0; j < 4; ++j) {
                const int lc = q4 * 4 + j;
                const int chs = lc ^ (m & 7);
                uint4 val = *reinterpret_cast<const uint4*>(&xS[m * 128 + chs * 8]);
                reinterpret_cast<uint4*>(V + (size_t)node * 128)[lc] = val;
            }
        }
    }
}

// ---------------------------------------------------------------------------
// Edge kernel v3.1: double-buffered LDS + async global_load_lds staging,
// WITH EXPLICIT vmcnt(0) DRAIN before every barrier (round-11 race fix).
// Per tile: 32 gll instructions (16 chunks x 2 tables), 8/wave, each writing
// 1024B = 4 edges x 256B. Global source carries the inverse of the read-side
// XOR swizzle (rule #21). One barrier/tile; out-store deferred via parity sbuf.
// ---------------------------------------------------------------------------
__global__ __launch_bounds__(256, 2)
void mlp_edges_uv3(const f16* __restrict__ U, const f16* __restrict__ V,
                   const int* __restrict__ srcI, const int* __restrict__ dstI,
                   const float* __restrict__ W2, const float* __restrict__ b2,
                   const float* __restrict__ W3, const float* __restrict__ b3,
                   float* __restrict__ out, int E, int ntiles)
{
    __shared__ f16 uS[2][64 * 128];    // 32 KB
    __shared__ f16 vS[2][64 * 128];    // 32 KB
    __shared__ float sbuf[2][4][64];   // 2 KB

    const int tid = threadIdx.x;
    const int w = tid >> 6, l = tid & 63, g = l >> 4, c = l & 15;
    const int grid = gridDim.x;

    // ---- W2 fragments + layer-3 constants ----
    f16x8 w2f[4][2];
    f32x4 b2v[2], w3v[2];
    #pragma unroll
    for (int nt = 0; nt < 2; ++nt) {
        const int n = w * 32 + nt * 16 + c;
        #pragma unroll
        for (int ks = 0; ks < 4; ++ks) {
            const float4* p = reinterpret_cast<const float4*>(W2 + n * 128 + ks * 32 + g * 8);
            float4 a = p[0], b = p[1];
            f16x8 v = { (f16)a.x,(f16)a.y,(f16)a.z,(f16)a.w,
                        (f16)b.x,(f16)b.y,(f16)b.z,(f16)b.w };
            w2f[ks][nt] = v;
        }
        const int base = w * 32 + nt * 16 + g * 4;
        b2v[nt] = *reinterpret_cast<const f32x4*>(b2 + base);
        w3v[nt] = *reinterpret_cast<const f32x4*>(W3 + base);
    }
    const float b3s = b3[0];

    // per-lane staging indices: instruction j of wave w covers edges
    // [ (w*4+j)*4, +4 ); lane l -> edge me = a*4 + (l>>4), slot p = l&15.
    int idxU[4], idxV[4];

    auto LOADIDX = [&](int t) {
        #pragma unroll
        for (int j = 0; j < 4; ++j) {
            const int me = (w * 4 + j) * 4 + (l >> 4);
            const int e = t * 64 + me;
            const bool ok = (t < ntiles) && (e < E);
            idxU[j] = ok ? srcI[e] : 0;
            idxV[j] = ok ? dstI[e] : 0;
        }
    };
    auto STAGE = [&](int buf) {
        #pragma unroll
        for (int j = 0; j < 4; ++j) {
            const int a = w * 4 + j;
            const int me = a * 4 + (l >> 4);
            const int ch = (l & 15) ^ (me & 7);      // pre-swizzled source chunk
            gll16(U + (size_t)idxU[j] * 128 + ch * 8, &uS[buf][a * 512]);
            gll16(V + (size_t)idxV[j] * 128 + ch * 8, &vS[buf][a * 512]);
        }
    };

    const int t0 = blockIdx.x;
    if (t0 >= ntiles) return;

    // prologue: stage tile t0 into buf 0; prefetch indices for t0+grid
    LOADIDX(t0);
    STAGE(0);
    LOADIDX(t0 + grid);

    int cur = 0;
    int lastT = t0;
    for (int t = t0; t < ntiles; t += grid) {
        drain_dma_and_barrier();   // buf[cur] DMA landed; sbuf[cur^1] published

        // deferred store of previous tile
        if (t != t0 && tid < 64) {
            const int pe = (t - grid) * 64 + tid;
            if (pe < E)
                out[pe] = sbuf[cur ^ 1][0][tid] + sbuf[cur ^ 1][1][tid]
                        + sbuf[cur ^ 1][2][tid] + sbuf[cur ^ 1][3][tid] + b3s;
        }

        // issue next tile's staging NOW — flies during this tile's compute
        if (t + grid < ntiles) {
            STAGE(cur ^ 1);
            LOADIDX(t + 2 * grid);
        }

        // ---- compute buf[cur]: GEMM2 with fused x1 = relu(u+v) ----
        f32x4 acc[4][2];
        #pragma unroll
        for (int et = 0; et < 4; ++et) { acc[et][0] = (f32x4){0,0,0,0}; acc[et][1] = (f32x4){0,0,0,0}; }
        #pragma unroll
        for (int ks = 0; ks < 4; ++ks) {
            #pragma unroll
            for (int et = 0; et < 4; ++et) {
                const int edge = et * 16 + c;
                const int chs = (ks * 4 + g) ^ (edge & 7);
                f16x8 uf = *reinterpret_cast<const f16x8*>(&uS[cur][edge * 128 + chs * 8]);
                f16x8 vf = *reinterpret_cast<const f16x8*>(&vS[cur][edge * 128 + chs * 8]);
                f16x8 xf = uf + vf;
                #pragma unroll
                for (int j = 0; j < 8; ++j) xf[j] = xf[j] > (f16)0 ? xf[j] : (f16)0;
                acc[et][0] = __builtin_amdgcn_mfma_f32_16x16x32_f16(w2f[ks][0], xf, acc[et][0], 0, 0, 0);
                acc[et][1] = __builtin_amdgcn_mfma_f32_16x16x32_f16(w2f[ks][1], xf, acc[et][1], 0, 0, 0);
            }
        }

        // ---- layer 3 (fp32) + in-wave reduce -> sbuf[cur] ----
        #pragma unroll
        for (int et = 0; et < 4; ++et) {
            f32x4 sv = {0.f,0.f,0.f,0.f};
            #pragma unroll
            for (int nt = 0; nt < 2; ++nt) {
                f32x4 v = acc[et][nt] + b2v[nt];
                #pragma unroll
                for (int r = 0; r < 4; ++r) {
                    float x = v[r] > 0.f ? v[r] : 0.f;
                    sv[r] += x * w3v[nt][r];
                }
            }
            float part = sv[0] + sv[1] + sv[2] + sv[3];
            part += __shfl_xor(part, 16, 64);
            part += __shfl_xor(part, 32, 64);
            if (g == 0) sbuf[cur][w][et * 16 + c] = part;
        }

        lastT = t;
        cur ^= 1;
    }

    // epilogue: publish + store the last tile
    drain_dma_and_barrier();
    if (tid < 64) {
        const int pe = lastT * 64 + tid;
        if (pe < E)
            out[pe] = sbuf[cur ^ 1][0][tid] + sbuf[cur ^ 1][1][tid]
                    + sbuf[cur ^ 1][2][tid] + sbuf[cur ^ 1][3][tid] + b3s;
    }
}

// ---------------------------------------------------------------------------
// Fallback (ws too small for U+V): round-7 proven kernel.
// ---------------------------------------------------------------------------
template<int USEF16>
__global__ __launch_bounds__(256, 3)
void mlp_edges(const float* __restrict__ h32, const f16* __restrict__ hf,
               const int* __restrict__ srcI, const int* __restrict__ dstI,
               const float* __restrict__ W1, const float* __restrict__ b1,
               const float* __restrict__ W2, const float* __restrict__ b2,
               const float* __restrict__ W3, const float* __restrict__ b3,
               float* __restrict__ out, int E, int ntiles)
{
    __shared__ f16 heS[64 * 256];
    __shared__ f16 x1S[64 * 128];
    __shared__ float sbuf[4][64];

    const int tid = threadIdx.x;
    const int w = tid >> 6, l = tid & 63, g = l >> 4, c = l & 15;
    const int grid = gridDim.x;

    f16x8 w1f[8][2], w2f[4][2];
    f32x4 b1v[2], b2v[2], w3v[2];
    #pragma unroll
    for (int nt = 0; nt < 2; ++nt) {
        const int n = w * 32 + nt * 16 + c;
        #pragma unroll
        for (int ks = 0; ks < 8; ++ks) {
            const float4* p = reinterpret_cast<const float4*>(W1 + n * 256 + ks * 32 + g * 8);
            float4 a = p[0], b = p[1];
            f16x8 v = { (f16)a.x,(f16)a.y,(f16)a.z,(f16)a.w,
                        (f16)b.x,(f16)b.y,(f16)b.z,(f16)b.w };
            w1f[ks][nt] = v;
        }
        #pragma unroll
        for (int ks = 0; ks < 4; ++ks) {
            const float4* p = reinterpret_cast<const float4*>(W2 + n * 128 + ks * 32 + g * 8);
            float4 a = p[0], b = p[1];
            f16x8 v = { (f16)a.x,(f16)a.y,(f16)a.z,(f16)a.w,
                        (f16)b.x,(f16)b.y,(f16)b.z,(f16)b.w };
            w2f[ks][nt] = v;
        }
        const int base = w * 32 + nt * 16 + g * 4;
        b1v[nt] = *reinterpret_cast<const f32x4*>(b1 + base);
        b2v[nt] = *reinterpret_cast<const f32x4*>(b2 + base);
        w3v[nt] = *reinterpret_cast<const f32x4*>(W3 + base);
    }
    const float b3s = b3[0];

    const int p_ = tid >> 1, q_ = tid & 1;
    const int m_ = p_ & 63;
    const int hh = p_ >> 6;
    const int* __restrict__ idxArr = hh ? dstI : srcI;

    auto loadIdx = [&](int t) -> int {
        int e = t * 64 + m_;
        return (e < E) ? idxArr[e] : 0;
    };
    auto stage = [&](int node) {
        if (USEF16) {
            const uint4* src = reinterpret_cast<const uint4*>(hf + (size_t)node * 128) + q_ * 8;
            #pragma unroll
            for (int j = 0; j < 8; ++j) {
                uint4 v = src[j];
                const int chs = (hh * 16 + q_ * 8 + j) ^ (m_ & 7);
                *reinterpret_cast<uint4*>(&heS[m_ * 256 + chs * 8]) = v;
            }
        } else {
            const float4* src = reinterpret_cast<const float4*>(h32 + (size_t)node * 128) + q_ * 16;
            #pragma unroll
            for (int j = 0; j < 8; ++j) {
                float4 a = src[2 * j], b = src[2 * j + 1];
                f16x8 v = { (f16)a.x,(f16)a.y,(f16)a.z,(f16)a.w,
                            (f16)b.x,(f16)b.y,(f16)b.z,(f16)b.w };
                const int chs = (hh * 16 + q_ * 8 + j) ^ (m_ & 7);
                *reinterpret_cast<f16x8*>(&heS[m_ * 256 + chs * 8]) = v;
            }
        }
    };

    const int t0 = blockIdx.x;
    int nIdx = (t0 < ntiles) ? loadIdx(t0) : 0;

    for (int t = t0; t < ntiles; t += grid) {
        stage(nIdx);
        __syncthreads();
        nIdx = (t + grid < ntiles) ? loadIdx(t + grid) : 0;

        f32x4 acc[4][2];
        #pragma unroll
        for (int et = 0; et < 4; ++et) { acc[et][0] = (f32x4){0,0,0,0}; acc[et][1] = (f32x4){0,0,0,0}; }
        #pragma unroll
        for (int ks = 0; ks < 8; ++ks) {
            #pragma unroll
            for (int et = 0; et < 4; ++et) {
                const int edge = et * 16 + c;
                const int chs = (ks * 4 + g) ^ (edge & 7);
                f16x8 hb = *reinterpret_cast<const f16x8*>(&heS[edge * 256 + chs * 8]);
                acc[et][0] = __builtin_amdgcn_mfma_f32_16x16x32_f16(w1f[ks][0], hb, acc[et][0], 0, 0, 0);
                acc[et][1] = __builtin_amdgcn_mfma_f32_16x16x32_f16(w1f[ks][1], hb, acc[et][1], 0, 0, 0);
            }
        }
        #pragma unroll
        for (int et = 0; et < 4; ++et) {
            #pragma unroll
            for (int nt = 0; nt < 2; ++nt) {
                f32x4 v = acc[et][nt] + b1v[nt];
                #pragma unroll
                for (int r = 0; r < 4; ++r) v[r] = v[r] > 0.f ? v[r] : 0.f;
                union { fp16x2 h2[2]; uint2 u; } uu;
                uu.h2[0] = __builtin_amdgcn_cvt_pkrtz(v[0], v[1]);
                uu.h2[1] = __builtin_amdgcn_cvt_pkrtz(v[2], v[3]);
                const int edge = et * 16 + c;
                const int n0 = w * 32 + nt * 16 + g * 4;
                const int chs = (n0 >> 3) ^ (edge & 7);
                *reinterpret_cast<uint2*>(&x1S[edge * 128 + chs * 8 + (n0 & 7)]) = uu.u;
            }
        }
        __syncthreads();

        #pragma unroll
        for (int et = 0; et < 4; ++et) { acc[et][0] = (f32x4){0,0,0,0}; acc[et][1] = (f32x4){0,0,0,0}; }
        #pragma unroll
        for (int ks = 0; ks < 4; ++ks) {
            #pragma unroll
            for (int et = 0; et < 4; ++et) {
                const int edge = et * 16 + c;
                const int chs = (ks * 4 + g) ^ (edge & 7);
                f16x8 xb = *reinterpret_cast<const f16x8*>(&x1S[edge * 128 + chs * 8]);
                acc[et][0] = __builtin_amdgcn_mfma_f32_16x16x32_f16(w2f[ks][0], xb, acc[et][0], 0, 0, 0);
                acc[et][1] = __builtin_amdgcn_mfma_f32_16x16x32_f16(w2f[ks][1], xb, acc[et][1], 0, 0, 0);
            }
        }
        #pragma unroll
        for (int et = 0; et < 4; ++et) {
            f32x4 sv = {0.f,0.f,0.f,0.f};
            #pragma unroll
            for (int nt = 0; nt < 2; ++nt) {
                f32x4 v = acc[et][nt] + b2v[nt];
                #pragma unroll
                for (int r = 0; r < 4; ++r) {
                    float x = v[r] > 0.f ? v[r] : 0.f;
                    sv[r] += x * w3v[nt][r];
                }
            }
            float part = sv[0] + sv[1] + sv[2] + sv[3];
            part += __shfl_xor(part, 16, 64);
            part += __shfl_xor(part, 32, 64);
            if (g == 0) sbuf[w][et * 16 + c] = part;
        }
        __syncthreads();

        if (tid < 64) {
            const int e = t * 64 + tid;
            if (e < E)
                out[e] = sbuf[0][tid] + sbuf[1][tid] + sbuf[2][tid] + sbuf[3][tid] + b3s;
        }
    }
}

// ---------------------------------------------------------------------------
extern "C" void kernel_launch(void* const* d_in, const int* in_sizes, int n_in,
                              void* d_out, int out_size, void* d_ws, size_t ws_size,
                              hipStream_t stream) {
    const float* h  = (const float*)d_in[0];
    const int* srcI = (const int*)d_in[1];
    const int* dstI = (const int*)d_in[2];
    const float* W1 = (const float*)d_in[3];
    const float* b1 = (const float*)d_in[4];
    const float* W2 = (const float*)d_in[5];
    const float* b2 = (const float*)d_in[6];
    const float* W3 = (const float*)d_in[7];
    const float* b3 = (const float*)d_in[8];
    float* out = (float*)d_out;

    const int E = in_sizes[1];
    const int hElems = in_sizes[0];        // nNodes * 128
    const int nNodes = hElems / 128;
    const int ntiles = (E + 63) / 64;

    const size_t uvBytes = 2 * (size_t)nNodes * 128 * sizeof(f16);   // U + V
    if (ws_size >= uvBytes) {
        f16* U = (f16*)d_ws;
        f16* V = U + (size_t)nNodes * 128;
        build_uv<<<(nNodes + 63) / 64, 256, 0, stream>>>(h, W1, b1, U, V, nNodes);
        const int grid = ntiles < 512 ? ntiles : 512;   // 2 blocks/CU (66 KB LDS)
        mlp_edges_uv3<<<grid, 256, 0, stream>>>(U, V, srcI, dstI, W2, b2, W3, b3, out, E, ntiles);
    } else {
        f16* hf = (f16*)d_ws;
        const bool useF16 = (ws_size >= (size_t)hElems * sizeof(f16));
        if (useF16) cvt_h_f16<<<2048, 256, 0, stream>>>(h, hf, hElems / 4);
        const int grid = ntiles < 768 ? ntiles : 768;
        if (useF16)
            mlp_edges<1><<<grid, 256, 0, stream>>>(h, hf, srcI, dstI, W1, b1, W2, b2, W3, b3, out, E, ntiles);
        else
            mlp_edges<0><<<grid, 256, 0, stream>>>(h, hf, srcI, dstI, W1, b1, W2, b2, W3, b3, out, E, ntiles);
    }
}